// Round 10
// baseline (284.072 us; speedup 1.0000x reference)
//
#include <hip/hip_runtime.h>
#include <cstdint>
#include <cstddef>

#define NNODES 20000
#define NEDGES 160000
#define DFEAT  128
#define NEXP   4

typedef unsigned short u16;
typedef __attribute__((ext_vector_type(8))) short short8v;   // 8 bf16 (4 VGPRs)
typedef __attribute__((ext_vector_type(4))) float float4v;   // 4 f32 acc

static __device__ __forceinline__ u16 f2bf(float f) {
    union { float f; unsigned int i; } v; v.f = f;
    unsigned int r = (v.i + 0x7FFFu + ((v.i >> 16) & 1u)) >> 16;  // RNE
    return (u16)r;
}
static __device__ __forceinline__ unsigned pack2(float a, float b) {
    return ((unsigned)f2bf(b) << 16) | f2bf(a);
}
static __device__ __forceinline__ float lo2f(unsigned int u) { return __uint_as_float(u << 16); }
static __device__ __forceinline__ float hi2f(unsigned int u) { return __uint_as_float(u & 0xFFFF0000u); }

static __device__ __forceinline__ void acc8(float w, uint4 v, float* a) {
    a[0] += w * lo2f(v.x); a[1] += w * hi2f(v.x);
    a[2] += w * lo2f(v.y); a[3] += w * hi2f(v.y);
    a[4] += w * lo2f(v.z); a[5] += w * hi2f(v.z);
    a[6] += w * lo2f(v.w); a[7] += w * hi2f(v.w);
}

// ---------------- workspace layout (float-element offsets; all 16B-aligned) --
// deg        0        [20000]  (zeroed)
// cursor     20000    [20000]  (zeroed)
// importance 40000    [8]      (zeroed)
// rowstart   40960    [20001] int
// csrc       61440    [160000] int
// cnrm       221440   [160000]
// gates      381440   [80000]
// W1t        461440   (65536 u16)  bf16 [4][128c][128k]
// W2t        494208   (65536 u16)
// xbf        526976   (2.56M u16)  bf16 [20000][128]
// h          1806976  (10.24M u16) bf16 [4][20000][128]
// end        6926976 floats = 27.7 MB

// ---- fused independent pre-work: deg | transpose(W) | gate | x->bf16 --------
// blocks [0,625): degree; [625,753): W transpose; [753,832): gate; [832,2082): xconv
__global__ void k_pre(const int* __restrict__ ei, const float* __restrict__ x,
                      const float* __restrict__ W1, const float* __restrict__ W2,
                      const float* __restrict__ x_agg, const float* __restrict__ w_gate,
                      const float* __restrict__ thr, const float* __restrict__ mask,
                      float* __restrict__ deg, u16* __restrict__ W1t, u16* __restrict__ W2t,
                      float* __restrict__ gates, float* __restrict__ importance,
                      u16* __restrict__ xbf) {
    int b = blockIdx.x;
    if (b < 625) {                       // ---- degree histogram
        int e = b * 256 + threadIdx.x;
        if (e < NEDGES) atomicAdd(&deg[ei[NEDGES + e]], 1.0f);
        return;
    }
    if (b < 753) {                       // ---- coalesced W transpose + bf16
        __shared__ u16 tile[32][33];
        int tb = b - 625;                // 0..127
        int arr = tb >> 6;
        int t6 = tb & 63;                // e(2) | ktile(2) | ctile(2)
        int e  = t6 >> 4;
        int kt = (t6 >> 2) & 3;
        int ct = t6 & 3;
        const float* W = arr ? W2 : W1;
        u16* Wt = arr ? W2t : W1t;
        int ty = threadIdx.x >> 5, tx = threadIdx.x & 31;
#pragma unroll
        for (int r = 0; r < 4; ++r) {    // read W[k][c] coalesced in c
            int k = kt * 32 + ty + r * 8;
            int c = ct * 32 + tx;
            tile[ty + r * 8][tx] = f2bf(W[(size_t)e * 16384 + (size_t)k * 128 + c]);
        }
        __syncthreads();
#pragma unroll
        for (int r = 0; r < 4; ++r) {    // write Wt[c][k] coalesced in k
            int c = ct * 32 + ty + r * 8;
            int k = kt * 32 + tx;
            Wt[(size_t)e * 16384 + (size_t)c * 128 + k] = tile[tx][ty + r * 8];
        }
        return;
    }
    if (b < 832) {                       // ---- gating (f32 exact)
        int n = (b - 753) * 256 + threadIdx.x;
        float4 lg = make_float4(0.f, 0.f, 0.f, 0.f);
        if (n < NNODES) {
            const float4* xr = (const float4*)(x_agg + (size_t)n * DFEAT);
            const float4* wg = (const float4*)w_gate;
            for (int k4 = 0; k4 < 32; ++k4) {
                float4 xv = xr[k4];
                float4 w0 = wg[4 * k4 + 0], w1 = wg[4 * k4 + 1];
                float4 w2 = wg[4 * k4 + 2], w3 = wg[4 * k4 + 3];
                lg.x += xv.x * w0.x + xv.y * w1.x + xv.z * w2.x + xv.w * w3.x;
                lg.y += xv.x * w0.y + xv.y * w1.y + xv.z * w2.y + xv.w * w3.y;
                lg.z += xv.x * w0.z + xv.y * w1.z + xv.z * w2.z + xv.w * w3.z;
                lg.w += xv.x * w0.w + xv.y * w1.w + xv.z * w2.w + xv.w * w3.w;
            }
        }
        float g[4];
        float lv[4] = {lg.x, lg.y, lg.z, lg.w};
        for (int e = 0; e < 4; ++e) {
            float sgm = 1.0f / (1.0f + expf(-lv[e]));
            g[e] = (sgm - thr[e] > 0.0f) ? mask[e] : 0.0f;
            if (n >= NNODES) g[e] = 0.0f;
        }
        if (n < NNODES) ((float4*)gates)[n] = make_float4(g[0], g[1], g[2], g[3]);
        int lane = threadIdx.x & 63;
        for (int e = 0; e < 4; ++e) {
            float v = g[e];
            for (int off = 32; off >= 1; off >>= 1) v += __shfl_down(v, off);
            if (lane == 0) atomicAdd(&importance[e], v);
        }
        return;
    }
    // ---- x -> bf16 (8 floats per thread)
    int t8 = (b - 832) * 256 + threadIdx.x;       // [0, 320000)
    const float4* xr = (const float4*)x + (size_t)t8 * 2;
    float4 v0 = xr[0], v1 = xr[1];
    uint4 o;
    o.x = pack2(v0.x, v0.y); o.y = pack2(v0.z, v0.w);
    o.z = pack2(v1.x, v1.y); o.w = pack2(v1.z, v1.w);
    ((uint4*)xbf)[t8] = o;
}

// ------------------------------------------------- exclusive scan (1 block)
__global__ void k_scan(const float* __restrict__ deg, int* __restrict__ rowstart) {
    __shared__ int part[1024];
    int t = threadIdx.x;
    const int PER = 20;
    int base = t * PER;
    int s = 0;
    for (int i = 0; i < PER; ++i) {
        int n = base + i;
        if (n < NNODES) s += (int)deg[n];
    }
    part[t] = s;
    __syncthreads();
    for (int off = 1; off < 1024; off <<= 1) {
        int v = (t >= off) ? part[t - off] : 0;
        __syncthreads();
        part[t] += v;
        __syncthreads();
    }
    int run = part[t] - s;
    for (int i = 0; i < PER; ++i) {
        int n = base + i;
        if (n < NNODES) {
            rowstart[n] = run;
            run += (int)deg[n];
        }
    }
    if (t == 1023) rowstart[NNODES] = part[1023];
}

// ------------------------------------------------------- CSR fill + norm
__global__ void k_fill(const int* __restrict__ ei, const float* __restrict__ deg,
                       const int* __restrict__ rowstart, int* __restrict__ cursor,
                       int* __restrict__ csrc, float* __restrict__ cnrm) {
    int e = blockIdx.x * 256 + threadIdx.x;
    if (e >= NEDGES) return;
    int s = ei[e], d = ei[NEDGES + e];
    int pos = atomicAdd(&cursor[d], 1);
    int slot = rowstart[d] + pos;
    csrc[slot] = s;
    float ds = fmaxf(deg[s], 1.0f), dd = fmaxf(deg[d], 1.0f);
    cnrm[slot] = 1.0f / sqrtf(ds * dd);
}

// ======== fused agg(x) -> LDS tile -> GEMM1 (all 4 experts) -> h =============
// grid 250 x 320 thr; block = 80 nodes; LDS tile [80 rows][17 uint4] (272B rows)
__launch_bounds__(320)
__global__ void k_ag1(const u16* __restrict__ xbf, const int* __restrict__ rowstart,
                      const int* __restrict__ csrc, const float* __restrict__ cnrm,
                      const u16* __restrict__ W1t, const float* __restrict__ b1,
                      u16* __restrict__ h) {
    __shared__ uint4 As[80 * 17];     // 21.76 KB
    int t = threadIdx.x;
    int nbase = blockIdx.x * 80;

    // ---- phase A: gather aggregated-x tile (bf16), 1280 items
    for (int it = t; it < 1280; it += 320) {
        int nl = it >> 4, l8 = it & 15;
        int node = nbase + nl;
        int r0 = rowstart[node], r1 = rowstart[node + 1];
        float a[8] = {0.f, 0.f, 0.f, 0.f, 0.f, 0.f, 0.f, 0.f};
        int j = r0;
        for (; j + 4 <= r1; j += 4) {
            int s0 = csrc[j], s1 = csrc[j + 1], s2 = csrc[j + 2], s3 = csrc[j + 3];
            float w0 = cnrm[j], w1 = cnrm[j + 1], w2 = cnrm[j + 2], w3 = cnrm[j + 3];
            uint4 v0 = ((const uint4*)(xbf + (size_t)s0 * DFEAT))[l8];
            uint4 v1 = ((const uint4*)(xbf + (size_t)s1 * DFEAT))[l8];
            uint4 v2 = ((const uint4*)(xbf + (size_t)s2 * DFEAT))[l8];
            uint4 v3 = ((const uint4*)(xbf + (size_t)s3 * DFEAT))[l8];
            acc8(w0, v0, a); acc8(w1, v1, a); acc8(w2, v2, a); acc8(w3, v3, a);
        }
        for (; j < r1; ++j) {
            uint4 v = ((const uint4*)(xbf + (size_t)csrc[j] * DFEAT))[l8];
            acc8(cnrm[j], v, a);
        }
        uint4 o;
        o.x = pack2(a[0], a[1]); o.y = pack2(a[2], a[3]);
        o.z = pack2(a[4], a[5]); o.w = pack2(a[6], a[7]);
        As[nl * 17 + l8] = o;
    }
    __syncthreads();

    // ---- phase B: GEMM over all 4 experts from the shared A-tile
    int w = t >> 6, l = t & 63;
    int lr = l & 15, kg = l >> 4;
    const short8v* As8 = (const short8v*)As;
    short8v a[4];
#pragma unroll
    for (int kk = 0; kk < 4; ++kk) a[kk] = As8[(w * 16 + lr) * 17 + kk * 4 + kg];

#pragma unroll
    for (int e = 0; e < NEXP; ++e) {
        const short8v* B8 = (const short8v*)(W1t + (size_t)e * 16384);
        u16* hb = h + (size_t)e * NNODES * DFEAT;
#pragma unroll
        for (int c = 0; c < 8; ++c) {
            float4v acc = {0.f, 0.f, 0.f, 0.f};
#pragma unroll
            for (int kk = 0; kk < 4; ++kk) {
                short8v bfr = B8[(c * 16 + lr) * 16 + kk * 4 + kg];
                acc = __builtin_amdgcn_mfma_f32_16x16x32_bf16(a[kk], bfr, acc, 0, 0, 0);
            }
            float bv = b1[e * DFEAT + c * 16 + lr];
#pragma unroll
            for (int i = 0; i < 4; ++i) {
                int node = nbase + w * 16 + kg * 4 + i;
                float vv = fmaxf(acc[i] + bv, 0.f);
                hb[(size_t)node * DFEAT + c * 16 + lr] = f2bf(vv);
            }
        }
    }
}

// ==== fused per-expert agg(h)->LDS->GEMM2 + gate-combine (+ loss) -> out =====
// grid 250 x 320 thr; block = 80 nodes; per expert: gather-or-zero, sync, MFMA
__launch_bounds__(320)
__global__ void k_ag2(const u16* __restrict__ h, const int* __restrict__ rowstart,
                      const int* __restrict__ csrc, const float* __restrict__ cnrm,
                      const u16* __restrict__ W2t, const float* __restrict__ b2,
                      const float* __restrict__ gates, const float* __restrict__ importance,
                      float* __restrict__ out) {
    if (blockIdx.x == 0 && threadIdx.x == 0) {
        float v0 = importance[0], v1 = importance[1], v2 = importance[2], v3 = importance[3];
        float mean = 0.25f * (v0 + v1 + v2 + v3);
        float d0 = v0 - mean, d1 = v1 - mean, d2 = v2 - mean, d3 = v3 - mean;
        float var = 0.25f * (d0 * d0 + d1 * d1 + d2 * d2 + d3 * d3);
        out[(size_t)NNODES * DFEAT] = 0.01f * var / (mean * mean + 1e-10f);
    }
    __shared__ uint4 As[80 * 17];     // 21.76 KB, reused per expert
    int t = threadIdx.x;
    int nbase = blockIdx.x * 80;
    int w = t >> 6, l = t & 63;
    int lr = l & 15, kg = l >> 4;
    const short8v* As8 = (const short8v*)As;

    float4v acc[8];
#pragma unroll
    for (int c = 0; c < 8; ++c) acc[c] = (float4v){0.f, 0.f, 0.f, 0.f};

    float gw[4];   // this thread's output-row gates for current expert

    for (int e = 0; e < NEXP; ++e) {
        __syncthreads();   // previous expert's MFMA reads of As done
        const u16* hb = h + (size_t)e * NNODES * DFEAT;
        // ---- gather-or-zero h_e tile
        for (int it = t; it < 1280; it += 320) {
            int nl = it >> 4, l8 = it & 15;
            int node = nbase + nl;
            uint4 o = make_uint4(0u, 0u, 0u, 0u);
            if (gates[(size_t)node * 4 + e] != 0.0f) {
                int r0 = rowstart[node], r1 = rowstart[node + 1];
                float a[8] = {0.f, 0.f, 0.f, 0.f, 0.f, 0.f, 0.f, 0.f};
                int j = r0;
                for (; j + 4 <= r1; j += 4) {
                    int s0 = csrc[j], s1 = csrc[j + 1], s2 = csrc[j + 2], s3 = csrc[j + 3];
                    float w0 = cnrm[j], w1 = cnrm[j + 1], w2 = cnrm[j + 2], w3 = cnrm[j + 3];
                    uint4 v0 = ((const uint4*)(hb + (size_t)s0 * DFEAT))[l8];
                    uint4 v1 = ((const uint4*)(hb + (size_t)s1 * DFEAT))[l8];
                    uint4 v2 = ((const uint4*)(hb + (size_t)s2 * DFEAT))[l8];
                    uint4 v3 = ((const uint4*)(hb + (size_t)s3 * DFEAT))[l8];
                    acc8(w0, v0, a); acc8(w1, v1, a); acc8(w2, v2, a); acc8(w3, v3, a);
                }
                for (; j < r1; ++j) {
                    uint4 v = ((const uint4*)(hb + (size_t)csrc[j] * DFEAT))[l8];
                    acc8(cnrm[j], v, a);
                }
                o.x = pack2(a[0], a[1]); o.y = pack2(a[2], a[3]);
                o.z = pack2(a[4], a[5]); o.w = pack2(a[6], a[7]);
            }
            As[nl * 17 + l8] = o;
        }
        __syncthreads();

        // ---- MFMA this expert, accumulate gated
        short8v a[4];
#pragma unroll
        for (int kk = 0; kk < 4; ++kk) a[kk] = As8[(w * 16 + lr) * 17 + kk * 4 + kg];
#pragma unroll
        for (int i = 0; i < 4; ++i)
            gw[i] = gates[(size_t)(nbase + w * 16 + kg * 4 + i) * 4 + e];
        const short8v* B8 = (const short8v*)(W2t + (size_t)e * 16384);
#pragma unroll
        for (int c = 0; c < 8; ++c) {
            float4v tv = {0.f, 0.f, 0.f, 0.f};
#pragma unroll
            for (int kk = 0; kk < 4; ++kk) {
                short8v bfr = B8[(c * 16 + lr) * 16 + kk * 4 + kg];
                tv = __builtin_amdgcn_mfma_f32_16x16x32_bf16(a[kk], bfr, tv, 0, 0, 0);
            }
            float bv = b2[e * DFEAT + c * 16 + lr];
#pragma unroll
            for (int i = 0; i < 4; ++i) acc[c][i] += gw[i] * (tv[i] + bv);
        }
    }

#pragma unroll
    for (int c = 0; c < 8; ++c)
#pragma unroll
        for (int i = 0; i < 4; ++i) {
            int node = nbase + w * 16 + kg * 4 + i;
            out[(size_t)node * DFEAT + c * 16 + lr] = acc[c][i];
        }
}

// --------------------------------------------------------------- launcher
extern "C" void kernel_launch(void* const* d_in, const int* in_sizes, int n_in,
                              void* d_out, int out_size, void* d_ws, size_t ws_size,
                              hipStream_t stream) {
    const float* x      = (const float*)d_in[0];
    const int*   ei     = (const int*)d_in[1];
    const float* x_agg  = (const float*)d_in[2];
    const float* w_gate = (const float*)d_in[3];
    const float* thr    = (const float*)d_in[4];
    const float* mask   = (const float*)d_in[5];
    const float* W1     = (const float*)d_in[6];
    const float* b1     = (const float*)d_in[7];
    const float* W2     = (const float*)d_in[8];
    const float* b2     = (const float*)d_in[9];
    float* out = (float*)d_out;
    float* ws  = (float*)d_ws;

    float* deg        = ws;
    int*   cursor     = (int*)(ws + 20000);
    float* importance = ws + 40000;
    int*   rowstart   = (int*)(ws + 40960);
    int*   csrc       = (int*)(ws + 61440);
    float* cnrm       = ws + 221440;
    float* gates      = ws + 381440;
    u16*   W1t        = (u16*)(ws + 461440);
    u16*   W2t        = (u16*)(ws + 494208);
    u16*   xbf        = (u16*)(ws + 526976);
    u16*   h          = (u16*)(ws + 1806976);

    hipMemsetAsync(d_ws, 0, 40008 * sizeof(float), stream);

    k_pre<<<2082, 256, 0, stream>>>(ei, x, W1, W2, x_agg, w_gate, thr, mask,
                                    deg, W1t, W2t, gates, importance, xbf);
    k_scan<<<1, 1024, 0, stream>>>(deg, rowstart);
    k_fill<<<(NEDGES + 255) / 256, 256, 0, stream>>>(ei, deg, rowstart, cursor, csrc, cnrm);
    k_ag1<<<250, 320, 0, stream>>>(xbf, rowstart, csrc, cnrm, W1t, b1, h);
    k_ag2<<<250, 320, 0, stream>>>(h, rowstart, csrc, cnrm, W2t, b2, gates, importance, out);
}

// Round 12
// 248.594 us; speedup vs baseline: 1.1427x; 1.1427x over previous
//
#include <hip/hip_runtime.h>
#include <cstdint>
#include <cstddef>

#define NNODES 20000
#define NEDGES 160000
#define DFEAT  128
#define NEXP   4

typedef unsigned short u16;
typedef __attribute__((ext_vector_type(8))) short short8v;   // 8 bf16 (4 VGPRs)
typedef __attribute__((ext_vector_type(4))) float float4v;   // 4 f32 acc

static __device__ __forceinline__ u16 f2bf(float f) {
    union { float f; unsigned int i; } v; v.f = f;
    unsigned int r = (v.i + 0x7FFFu + ((v.i >> 16) & 1u)) >> 16;  // RNE
    return (u16)r;
}
static __device__ __forceinline__ unsigned pack2(float a, float b) {
    return ((unsigned)f2bf(b) << 16) | f2bf(a);
}
static __device__ __forceinline__ float lo2f(unsigned int u) { return __uint_as_float(u << 16); }
static __device__ __forceinline__ float hi2f(unsigned int u) { return __uint_as_float(u & 0xFFFF0000u); }

static __device__ __forceinline__ void acc8(float w, uint4 v, float* a) {
    a[0] += w * lo2f(v.x); a[1] += w * hi2f(v.x);
    a[2] += w * lo2f(v.y); a[3] += w * hi2f(v.y);
    a[4] += w * lo2f(v.z); a[5] += w * hi2f(v.z);
    a[6] += w * lo2f(v.w); a[7] += w * hi2f(v.w);
}

// ---------------- workspace layout (float-element offsets; all 16B-aligned) --
// deg        0        [20000]  (zeroed)
// cursor     20000    [20000]  (zeroed)
// importance 40000    [8]      (zeroed)
// rowstart   40960    [20001] int
// csrc       61440    [160000] int
// cnrm       221440   [160000]
// gates      381440   [80000]
// W1t        461440   (65536 u16)  bf16 [4][128c][128k]
// W2t        494208   (65536 u16)
// xbf        526976   (2.56M u16)  bf16 [20000][128]
// h          1806976  (10.24M u16) bf16 [4][20000][128]

// ---- fused independent pre-work: deg | transpose(W) | gate | x->bf16 --------
// blocks [0,625): degree; [625,753): W transpose; [753,832): gate; [832,2082): xconv
__global__ void k_pre(const int* __restrict__ ei, const float* __restrict__ x,
                      const float* __restrict__ W1, const float* __restrict__ W2,
                      const float* __restrict__ x_agg, const float* __restrict__ w_gate,
                      const float* __restrict__ thr, const float* __restrict__ mask,
                      float* __restrict__ deg, u16* __restrict__ W1t, u16* __restrict__ W2t,
                      float* __restrict__ gates, float* __restrict__ importance,
                      u16* __restrict__ xbf) {
    int b = blockIdx.x;
    if (b < 625) {                       // ---- degree histogram
        int e = b * 256 + threadIdx.x;
        if (e < NEDGES) atomicAdd(&deg[ei[NEDGES + e]], 1.0f);
        return;
    }
    if (b < 753) {                       // ---- coalesced W transpose + bf16
        __shared__ u16 tile[32][33];
        int tb = b - 625;                // 0..127
        int arr = tb >> 6;
        int t6 = tb & 63;                // e(2) | ktile(2) | ctile(2)
        int e  = t6 >> 4;
        int kt = (t6 >> 2) & 3;
        int ct = t6 & 3;
        const float* W = arr ? W2 : W1;
        u16* Wt = arr ? W2t : W1t;
        int ty = threadIdx.x >> 5, tx = threadIdx.x & 31;
#pragma unroll
        for (int r = 0; r < 4; ++r) {    // read W[k][c] coalesced in c
            int k = kt * 32 + ty + r * 8;
            int c = ct * 32 + tx;
            tile[ty + r * 8][tx] = f2bf(W[(size_t)e * 16384 + (size_t)k * 128 + c]);
        }
        __syncthreads();
#pragma unroll
        for (int r = 0; r < 4; ++r) {    // write Wt[c][k] coalesced in k
            int c = ct * 32 + ty + r * 8;
            int k = kt * 32 + tx;
            Wt[(size_t)e * 16384 + (size_t)c * 128 + k] = tile[tx][ty + r * 8];
        }
        return;
    }
    if (b < 832) {                       // ---- gating (f32 exact)
        int n = (b - 753) * 256 + threadIdx.x;
        float4 lg = make_float4(0.f, 0.f, 0.f, 0.f);
        if (n < NNODES) {
            const float4* xr = (const float4*)(x_agg + (size_t)n * DFEAT);
            const float4* wg = (const float4*)w_gate;
            for (int k4 = 0; k4 < 32; ++k4) {
                float4 xv = xr[k4];
                float4 w0 = wg[4 * k4 + 0], w1 = wg[4 * k4 + 1];
                float4 w2 = wg[4 * k4 + 2], w3 = wg[4 * k4 + 3];
                lg.x += xv.x * w0.x + xv.y * w1.x + xv.z * w2.x + xv.w * w3.x;
                lg.y += xv.x * w0.y + xv.y * w1.y + xv.z * w2.y + xv.w * w3.y;
                lg.z += xv.x * w0.z + xv.y * w1.z + xv.z * w2.z + xv.w * w3.z;
                lg.w += xv.x * w0.w + xv.y * w1.w + xv.z * w2.w + xv.w * w3.w;
            }
        }
        float g[4];
        float lv[4] = {lg.x, lg.y, lg.z, lg.w};
        for (int e = 0; e < 4; ++e) {
            float sgm = 1.0f / (1.0f + expf(-lv[e]));
            g[e] = (sgm - thr[e] > 0.0f) ? mask[e] : 0.0f;
            if (n >= NNODES) g[e] = 0.0f;
        }
        if (n < NNODES) ((float4*)gates)[n] = make_float4(g[0], g[1], g[2], g[3]);
        int lane = threadIdx.x & 63;
        for (int e = 0; e < 4; ++e) {
            float v = g[e];
            for (int off = 32; off >= 1; off >>= 1) v += __shfl_down(v, off);
            if (lane == 0) atomicAdd(&importance[e], v);
        }
        return;
    }
    // ---- x -> bf16 (8 floats per thread)
    int t8 = (b - 832) * 256 + threadIdx.x;       // [0, 320000)
    const float4* xr = (const float4*)x + (size_t)t8 * 2;
    float4 v0 = xr[0], v1 = xr[1];
    uint4 o;
    o.x = pack2(v0.x, v0.y); o.y = pack2(v0.z, v0.w);
    o.z = pack2(v1.x, v1.y); o.w = pack2(v1.z, v1.w);
    ((uint4*)xbf)[t8] = o;
}

// ------------------------------------------------- exclusive scan (1 block)
__global__ void k_scan(const float* __restrict__ deg, int* __restrict__ rowstart) {
    __shared__ int part[1024];
    int t = threadIdx.x;
    const int PER = 20;
    int base = t * PER;
    int s = 0;
    for (int i = 0; i < PER; ++i) {
        int n = base + i;
        if (n < NNODES) s += (int)deg[n];
    }
    part[t] = s;
    __syncthreads();
    for (int off = 1; off < 1024; off <<= 1) {
        int v = (t >= off) ? part[t - off] : 0;
        __syncthreads();
        part[t] += v;
        __syncthreads();
    }
    int run = part[t] - s;
    for (int i = 0; i < PER; ++i) {
        int n = base + i;
        if (n < NNODES) {
            rowstart[n] = run;
            run += (int)deg[n];
        }
    }
    if (t == 1023) rowstart[NNODES] = part[1023];
}

// ------------------------------------------------------- CSR fill + norm
__global__ void k_fill(const int* __restrict__ ei, const float* __restrict__ deg,
                       const int* __restrict__ rowstart, int* __restrict__ cursor,
                       int* __restrict__ csrc, float* __restrict__ cnrm) {
    int e = blockIdx.x * 256 + threadIdx.x;
    if (e >= NEDGES) return;
    int s = ei[e], d = ei[NEDGES + e];
    int pos = atomicAdd(&cursor[d], 1);
    int slot = rowstart[d] + pos;
    csrc[slot] = s;
    float ds = fmaxf(deg[s], 1.0f), dd = fmaxf(deg[d], 1.0f);
    cnrm[slot] = 1.0f / sqrtf(ds * dd);
}

// ======== fused agg(x) -> LDS tile -> GEMM1 (all 4 experts) -> h =============
// grid 625 x 256 thr (4 waves); block = 32 nodes; LDS [32][17] uint4 = 8.7 KB
__launch_bounds__(256)
__global__ void k_ag1(const u16* __restrict__ xbf, const int* __restrict__ rowstart,
                      const int* __restrict__ csrc, const float* __restrict__ cnrm,
                      const u16* __restrict__ W1t, const float* __restrict__ b1,
                      u16* __restrict__ h) {
    __shared__ uint4 As[32 * 17];
    int t = threadIdx.x;
    int nbase = blockIdx.x * 32;

    // ---- phase A: gather aggregated-x tile (bf16), 512 items, 2/thread
    for (int it = t; it < 512; it += 256) {
        int nl = it >> 4, l8 = it & 15;
        int node = nbase + nl;
        int r0 = rowstart[node], r1 = rowstart[node + 1];
        float a[8] = {0.f, 0.f, 0.f, 0.f, 0.f, 0.f, 0.f, 0.f};
        int j = r0;
        for (; j + 4 <= r1; j += 4) {
            int s0 = csrc[j], s1 = csrc[j + 1], s2 = csrc[j + 2], s3 = csrc[j + 3];
            float w0 = cnrm[j], w1 = cnrm[j + 1], w2 = cnrm[j + 2], w3 = cnrm[j + 3];
            uint4 v0 = ((const uint4*)(xbf + (size_t)s0 * DFEAT))[l8];
            uint4 v1 = ((const uint4*)(xbf + (size_t)s1 * DFEAT))[l8];
            uint4 v2 = ((const uint4*)(xbf + (size_t)s2 * DFEAT))[l8];
            uint4 v3 = ((const uint4*)(xbf + (size_t)s3 * DFEAT))[l8];
            acc8(w0, v0, a); acc8(w1, v1, a); acc8(w2, v2, a); acc8(w3, v3, a);
        }
        for (; j < r1; ++j) {
            uint4 v = ((const uint4*)(xbf + (size_t)csrc[j] * DFEAT))[l8];
            acc8(cnrm[j], v, a);
        }
        uint4 o;
        o.x = pack2(a[0], a[1]); o.y = pack2(a[2], a[3]);
        o.z = pack2(a[4], a[5]); o.w = pack2(a[6], a[7]);
        As[nl * 17 + l8] = o;
    }
    __syncthreads();

    // ---- phase B: GEMM all 4 experts; wave w: rows (w&1)*16, cols (w>>1)*64
    int w = t >> 6, l = t & 63;
    int rh = w & 1, ch = w >> 1;
    int lr = l & 15, kg = l >> 4;
    const short8v* As8 = (const short8v*)As;
    short8v a[4];
#pragma unroll
    for (int kk = 0; kk < 4; ++kk) a[kk] = As8[(rh * 16 + lr) * 17 + kk * 4 + kg];

#pragma unroll
    for (int e = 0; e < NEXP; ++e) {
        const short8v* B8 = (const short8v*)(W1t + (size_t)e * 16384);
        u16* hb = h + (size_t)e * NNODES * DFEAT;
#pragma unroll
        for (int c = 0; c < 4; ++c) {
            float4v acc = {0.f, 0.f, 0.f, 0.f};
#pragma unroll
            for (int kk = 0; kk < 4; ++kk) {
                short8v bfr = B8[((ch * 4 + c) * 16 + lr) * 16 + kk * 4 + kg];
                acc = __builtin_amdgcn_mfma_f32_16x16x32_bf16(a[kk], bfr, acc, 0, 0, 0);
            }
            float bv = b1[e * DFEAT + (ch * 4 + c) * 16 + lr];
#pragma unroll
            for (int i = 0; i < 4; ++i) {
                int node = nbase + rh * 16 + kg * 4 + i;
                float vv = fmaxf(acc[i] + bv, 0.f);
                hb[(size_t)node * DFEAT + (ch * 4 + c) * 16 + lr] = f2bf(vv);
            }
        }
    }
}

// ==== fused agg(h, all experts) -> 4 LDS tiles -> GEMM2+combine (+loss) ======
// grid 625 x 256 thr; block = 32 nodes; LDS [4][32][17] uint4 = 34.8 KB
// single barrier pair: gather all 4 expert tiles (gate-skip), then MFMA loop
__launch_bounds__(256)
__global__ void k_ag2(const u16* __restrict__ h, const int* __restrict__ rowstart,
                      const int* __restrict__ csrc, const float* __restrict__ cnrm,
                      const u16* __restrict__ W2t, const float* __restrict__ b2,
                      const float* __restrict__ gates, const float* __restrict__ importance,
                      float* __restrict__ out) {
    if (blockIdx.x == 0 && threadIdx.x == 0) {
        float v0 = importance[0], v1 = importance[1], v2 = importance[2], v3 = importance[3];
        float mean = 0.25f * (v0 + v1 + v2 + v3);
        float d0 = v0 - mean, d1 = v1 - mean, d2 = v2 - mean, d3 = v3 - mean;
        float var = 0.25f * (d0 * d0 + d1 * d1 + d2 * d2 + d3 * d3);
        out[(size_t)NNODES * DFEAT] = 0.01f * var / (mean * mean + 1e-10f);
    }
    __shared__ uint4 As[4 * 32 * 17];
    int t = threadIdx.x;
    int nbase = blockIdx.x * 32;

    // ---- gather phase: 2048 items = (e, node, l8); gate-skip -> zero tile
    for (int it = t; it < 2048; it += 256) {
        int e = it >> 9;
        int rem = it & 511;
        int nl = rem >> 4, l8 = rem & 15;
        int node = nbase + nl;
        uint4 o = make_uint4(0u, 0u, 0u, 0u);
        if (gates[(size_t)node * 4 + e] != 0.0f) {
            const u16* hb = h + (size_t)e * NNODES * DFEAT;
            int r0 = rowstart[node], r1 = rowstart[node + 1];
            float a[8] = {0.f, 0.f, 0.f, 0.f, 0.f, 0.f, 0.f, 0.f};
            int j = r0;
            for (; j + 4 <= r1; j += 4) {
                int s0 = csrc[j], s1 = csrc[j + 1], s2 = csrc[j + 2], s3 = csrc[j + 3];
                float w0 = cnrm[j], w1 = cnrm[j + 1], w2 = cnrm[j + 2], w3 = cnrm[j + 3];
                uint4 v0 = ((const uint4*)(hb + (size_t)s0 * DFEAT))[l8];
                uint4 v1 = ((const uint4*)(hb + (size_t)s1 * DFEAT))[l8];
                uint4 v2 = ((const uint4*)(hb + (size_t)s2 * DFEAT))[l8];
                uint4 v3 = ((const uint4*)(hb + (size_t)s3 * DFEAT))[l8];
                acc8(w0, v0, a); acc8(w1, v1, a); acc8(w2, v2, a); acc8(w3, v3, a);
            }
            for (; j < r1; ++j) {
                uint4 v = ((const uint4*)(hb + (size_t)csrc[j] * DFEAT))[l8];
                acc8(cnrm[j], v, a);
            }
            o.x = pack2(a[0], a[1]); o.y = pack2(a[2], a[3]);
            o.z = pack2(a[4], a[5]); o.w = pack2(a[6], a[7]);
        }
        As[(e * 32 + nl) * 17 + l8] = o;
    }
    __syncthreads();

    // ---- MFMA phase: wave w: rows (w&1)*16, cols (w>>1)*64; acc over experts
    int w = t >> 6, l = t & 63;
    int rh = w & 1, ch = w >> 1;
    int lr = l & 15, kg = l >> 4;
    const short8v* As8 = (const short8v*)As;

    float4v acc[4];
#pragma unroll
    for (int c = 0; c < 4; ++c) acc[c] = (float4v){0.f, 0.f, 0.f, 0.f};

#pragma unroll
    for (int e = 0; e < NEXP; ++e) {
        short8v a[4];
#pragma unroll
        for (int kk = 0; kk < 4; ++kk)
            a[kk] = As8[((e * 32) + rh * 16 + lr) * 17 + kk * 4 + kg];
        float gw[4];
#pragma unroll
        for (int i = 0; i < 4; ++i)
            gw[i] = gates[(size_t)(nbase + rh * 16 + kg * 4 + i) * 4 + e];
        const short8v* B8 = (const short8v*)(W2t + (size_t)e * 16384);
#pragma unroll
        for (int c = 0; c < 4; ++c) {
            float4v tv = {0.f, 0.f, 0.f, 0.f};
#pragma unroll
            for (int kk = 0; kk < 4; ++kk) {
                short8v bfr = B8[((ch * 4 + c) * 16 + lr) * 16 + kk * 4 + kg];
                tv = __builtin_amdgcn_mfma_f32_16x16x32_bf16(a[kk], bfr, tv, 0, 0, 0);
            }
            float bv = b2[e * DFEAT + (ch * 4 + c) * 16 + lr];
#pragma unroll
            for (int i = 0; i < 4; ++i) acc[c][i] += gw[i] * (tv[i] + bv);
        }
    }

#pragma unroll
    for (int c = 0; c < 4; ++c)
#pragma unroll
        for (int i = 0; i < 4; ++i) {
            int node = nbase + rh * 16 + kg * 4 + i;
            out[(size_t)node * DFEAT + (ch * 4 + c) * 16 + lr] = acc[c][i];
        }
}

// --------------------------------------------------------------- launcher
extern "C" void kernel_launch(void* const* d_in, const int* in_sizes, int n_in,
                              void* d_out, int out_size, void* d_ws, size_t ws_size,
                              hipStream_t stream) {
    const float* x      = (const float*)d_in[0];
    const int*   ei     = (const int*)d_in[1];
    const float* x_agg  = (const float*)d_in[2];
    const float* w_gate = (const float*)d_in[3];
    const float* thr    = (const float*)d_in[4];
    const float* mask   = (const float*)d_in[5];
    const float* W1     = (const float*)d_in[6];
    const float* b1     = (const float*)d_in[7];
    const float* W2     = (const float*)d_in[8];
    const float* b2     = (const float*)d_in[9];
    float* out = (float*)d_out;
    float* ws  = (float*)d_ws;

    float* deg        = ws;
    int*   cursor     = (int*)(ws + 20000);
    float* importance = ws + 40000;
    int*   rowstart   = (int*)(ws + 40960);
    int*   csrc       = (int*)(ws + 61440);
    float* cnrm       = ws + 221440;
    float* gates      = ws + 381440;
    u16*   W1t        = (u16*)(ws + 461440);
    u16*   W2t        = (u16*)(ws + 494208);
    u16*   xbf        = (u16*)(ws + 526976);
    u16*   h          = (u16*)(ws + 1806976);

    hipMemsetAsync(d_ws, 0, 40008 * sizeof(float), stream);

    k_pre<<<2082, 256, 0, stream>>>(ei, x, W1, W2, x_agg, w_gate, thr, mask,
                                    deg, W1t, W2t, gates, importance, xbf);
    k_scan<<<1, 1024, 0, stream>>>(deg, rowstart);
    k_fill<<<(NEDGES + 255) / 256, 256, 0, stream>>>(ei, deg, rowstart, cursor, csrc, cnrm);
    k_ag1<<<625, 256, 0, stream>>>(xbf, rowstart, csrc, cnrm, W1t, b1, h);
    k_ag2<<<625, 256, 0, stream>>>(h, rowstart, csrc, cnrm, W2t, b2, gates, importance, out);
}